// Round 1
// baseline (123.945 us; speedup 1.0000x reference)
//
#include <hip/hip_runtime.h>
#include <math.h>

#define Bn 2
#define Nn 384
#define Cc 16
#define Hh 64
#define NBk 10
#define NT 64            // n-tile per conv block
#define MCH 48           // m-chunks (grid split over m)
#define MB (Nn/MCH)      // 8 m's per block
#define BNC (Bn*Nn*Cc)   // 12288
#define SCALE 0.05103103630798288f   // 1/sqrt(384)

// W2x[b,m,h,i] = sum_j w2[h, i*16+j] * xin[b,m,j]   (xin masked by diag(mask) if mask!=null path)
__global__ __launch_bounds__(256) void k_w2x_from_x(
    const float* __restrict__ x, const int* __restrict__ mask,
    const float* __restrict__ w2, float* __restrict__ w2x)
{
    __shared__ float xs[Cc];
    const int bm = blockIdx.x;           // b*N + m
    const int b = bm / Nn, m = bm % Nn;
    const int tid = threadIdx.x;
    if (tid < Cc) {
        int keep = mask[(size_t)b*Nn*Nn + (size_t)m*Nn + m];
        xs[tid] = keep ? x[(size_t)bm*Cc + tid] : 0.0f;
    }
    __syncthreads();
    const int h = tid >> 2, ig = tid & 3;
    float oc[4];
    #pragma unroll
    for (int c = 0; c < 4; ++c) {
        const int i = ig*4 + c;
        float acc = 0.f;
        #pragma unroll
        for (int jg = 0; jg < 4; ++jg) {
            float4 wv = *reinterpret_cast<const float4*>(w2 + h*256 + i*16 + jg*4);
            acc += wv.x*xs[jg*4+0] + wv.y*xs[jg*4+1] + wv.z*xs[jg*4+2] + wv.w*xs[jg*4+3];
        }
        oc[c] = acc;
    }
    float4 o; o.x=oc[0]; o.y=oc[1]; o.z=oc[2]; o.w=oc[3];
    *reinterpret_cast<float4*>(w2x + (size_t)bm*(Hh*Cc) + tid*4) = o;
}

// same, but xin = sum over m-chunks of part (conv1 output), no mask
__global__ __launch_bounds__(256) void k_w2x_from_part(
    const float* __restrict__ part, const float* __restrict__ w2, float* __restrict__ w2x)
{
    __shared__ float xs[Cc];
    const int bm = blockIdx.x;
    const int tid = threadIdx.x;
    if (tid < Cc) {
        float s = 0.f;
        for (int chk = 0; chk < MCH; ++chk)
            s += part[(size_t)chk*BNC + (size_t)bm*Cc + tid];
        xs[tid] = s;
    }
    __syncthreads();
    const int h = tid >> 2, ig = tid & 3;
    float oc[4];
    #pragma unroll
    for (int c = 0; c < 4; ++c) {
        const int i = ig*4 + c;
        float acc = 0.f;
        #pragma unroll
        for (int jg = 0; jg < 4; ++jg) {
            float4 wv = *reinterpret_cast<const float4*>(w2 + h*256 + i*16 + jg*4);
            acc += wv.x*xs[jg*4+0] + wv.y*xs[jg*4+1] + wv.z*xs[jg*4+2] + wv.w*xs[jg*4+3];
        }
        oc[c] = acc;
    }
    float4 o; o.x=oc[0]; o.y=oc[1]; o.z=oc[2]; o.w=oc[3];
    *reinterpret_cast<float4*>(w2x + (size_t)bm*(Hh*Cc) + tid*4) = o;
}

// out_part[ch,b,n,i] = SCALE * sum_{m in chunk} sum_h swish(rbf(r_nm)@w1)[h] * W2x[b,m,h,i]
__global__ __launch_bounds__(256) void k_conv(
    const float* __restrict__ xyz, const float* __restrict__ w1,
    const float* __restrict__ w2x, float* __restrict__ part)
{
    __shared__ float w1s[NBk*Hh];      // 640
    __shared__ float xyzn[NT*3];       // 192
    __shared__ float rbfs[NT*NBk];     // 640
    __shared__ float w2xs[Hh*Cc];      // 1024
    __shared__ float red[8*32*Cc];     // 4096

    const int tid = threadIdx.x;
    const int ns = tid & 31;           // n slot
    const int hg = tid >> 5;           // h group (0..7)
    const int h0 = hg * 8;
    const int b  = blockIdx.z;
    const int n0 = blockIdx.y * NT;
    const int m0 = blockIdx.x * MB;
    const int ch = blockIdx.x;

    for (int idx = tid; idx < NBk*Hh; idx += 256) w1s[idx] = w1[idx];
    if (tid < NT*3) xyzn[tid] = xyz[((size_t)b*Nn + n0)*3 + tid];

    float acc0[Cc], acc1[Cc];
    #pragma unroll
    for (int i = 0; i < Cc; ++i) { acc0[i] = 0.f; acc1[i] = 0.f; }

    for (int mi = 0; mi < MB; ++mi) {
        const int m = m0 + mi;
        __syncthreads();   // protect LDS from previous iteration readers
        // stage W2x[b,m] tile (1024 floats) into LDS, coalesced
        float4 wv = *reinterpret_cast<const float4*>(w2x + ((size_t)(b*Nn + m))*(Hh*Cc) + tid*4);
        *reinterpret_cast<float4*>(w2xs + tid*4) = wv;
        // cooperative rbf for all 64 n's of the tile (dedupe exps)
        if (tid < NT) {
            const float* xm = xyz + ((size_t)b*Nn + m)*3;
            float dx = xyzn[tid*3+0] - xm[0];
            float dy = xyzn[tid*3+1] - xm[1];
            float dz = xyzn[tid*3+2] - xm[2];
            float r = sqrtf(dx*dx + dy*dy + dz*dz + 1e-12f);
            #pragma unroll
            for (int k = 0; k < NBk; ++k) {
                float u = r - (float)k * (10.0f/9.0f);
                rbfs[tid*NBk + k] = __expf(-u*u);
            }
        }
        __syncthreads();
        #pragma unroll
        for (int p = 0; p < 2; ++p) {
            const int nn = ns + p*32;
            float rb[NBk];
            #pragma unroll
            for (int k = 0; k < NBk; ++k) rb[k] = rbfs[nn*NBk + k];
            float hid[8];
            #pragma unroll
            for (int j = 0; j < 8; ++j) {
                float v = 0.f;
                #pragma unroll
                for (int k = 0; k < NBk; ++k) v += rb[k] * w1s[k*Hh + h0 + j];
                hid[j] = v * __builtin_amdgcn_rcpf(1.0f + __expf(-v));  // swish
            }
            float* accp = p ? acc1 : acc0;
            #pragma unroll
            for (int j = 0; j < 8; ++j) {
                const float hj = hid[j];
                const float4* wp = reinterpret_cast<const float4*>(w2xs + (h0+j)*Cc);
                #pragma unroll
                for (int ig = 0; ig < 4; ++ig) {
                    float4 w = wp[ig];
                    accp[ig*4+0] += hj * w.x;
                    accp[ig*4+1] += hj * w.y;
                    accp[ig*4+2] += hj * w.z;
                    accp[ig*4+3] += hj * w.w;
                }
            }
        }
    }

    // reduce over the 8 h-groups, write partials
    #pragma unroll
    for (int p = 0; p < 2; ++p) {
        const float* accp = p ? acc1 : acc0;
        __syncthreads();
        #pragma unroll
        for (int i = 0; i < Cc; ++i) red[(hg*32 + ns)*Cc + i] = accp[i];
        __syncthreads();
        for (int o = tid; o < 32*Cc; o += 256) {
            const int n = o >> 4, i = o & 15;
            float s = 0.f;
            #pragma unroll
            for (int g = 0; g < 8; ++g) s += red[(g*32 + n)*Cc + i];
            part[(((size_t)ch*Bn + b)*Nn + (n0 + p*32 + n))*Cc + i] = s * SCALE;
        }
    }
}

// x2[b,n,i] = keep(b,n) ? sum_ch part2[ch,b,n,i] : 0
__global__ __launch_bounds__(256) void k_reduce_mask(
    const float* __restrict__ part, const int* __restrict__ mask, float* __restrict__ x2)
{
    const int t = blockIdx.x*256 + threadIdx.x;   // < BNC
    const int b = t / (Nn*Cc);
    const int n = (t / Cc) % Nn;
    float s = 0.f;
    for (int chk = 0; chk < MCH; ++chk) s += part[(size_t)chk*BNC + t];
    const int keep = mask[(size_t)b*Nn*Nn + (size_t)n*Nn + n];
    x2[t] = keep ? s : 0.f;
}

// sum over n -> normalize (ddof=1) -> @fc2^T -> softmax
__global__ __launch_bounds__(256) void k_finalize(
    const float* __restrict__ x2, const float* __restrict__ fc2, float* __restrict__ out)
{
    __shared__ float redf[8*32];
    const int tid = threadIdx.x;
    const int pair = tid & 31, ng = tid >> 5;
    const int b = pair >> 4, i = pair & 15;
    float s = 0.f;
    for (int n = ng; n < Nn; n += 8) s += x2[((size_t)b*Nn + n)*Cc + i];
    redf[ng*32 + pair] = s;
    __syncthreads();
    if (tid < 32) {
        float v = 0.f;
        #pragma unroll
        for (int g = 0; g < 8; ++g) v += redf[g*32 + tid];
        // mean over the 16 channels (lanes 0-15: b=0, 16-31: b=1)
        float sum = v;
        #pragma unroll
        for (int d = 1; d < 16; d <<= 1) sum += __shfl_xor(sum, d, 32);
        const float mean = sum * (1.0f/16.0f);
        const float c0 = v - mean;
        float vs = c0*c0;
        #pragma unroll
        for (int d = 1; d < 16; d <<= 1) vs += __shfl_xor(vs, d, 32);
        const float nv = c0 / (sqrtf(vs * (1.0f/15.0f)) + 1e-6f);  // std ddof=1 + eps
        // y[b,i] = sum_j nv[b,j] * fc2[i,j]
        float y = 0.f;
        #pragma unroll
        for (int j = 0; j < 16; ++j) {
            float nj = __shfl(nv, (tid & 16) + j, 32);
            y += nj * fc2[i*16 + j];
        }
        // softmax over i within each 16-lane group
        float mx = y;
        #pragma unroll
        for (int d = 1; d < 16; d <<= 1) mx = fmaxf(mx, __shfl_xor(mx, d, 32));
        const float e = __expf(y - mx);
        float es = e;
        #pragma unroll
        for (int d = 1; d < 16; d <<= 1) es += __shfl_xor(es, d, 32);
        out[b*Cc + i] = e / es;
    }
}

extern "C" void kernel_launch(void* const* d_in, const int* in_sizes, int n_in,
                              void* d_out, int out_size, void* d_ws, size_t ws_size,
                              hipStream_t stream) {
    const float* x    = (const float*)d_in[0];
    const float* xyz  = (const float*)d_in[1];
    const int*   mask = (const int*)  d_in[2];
    const float* c1w1 = (const float*)d_in[3];
    const float* c1w2 = (const float*)d_in[4];
    const float* c2w1 = (const float*)d_in[5];
    const float* c2w2 = (const float*)d_in[6];
    const float* fc2  = (const float*)d_in[7];
    float* out = (float*)d_out;

    float* A  = (float*)d_ws;                       // W2x buffer: B*N*H*C = 786432 floats
    float* P  = A + (size_t)Bn*Nn*Hh*Cc;            // partials:  MCH*B*N*C = 589824 floats
    float* X2 = P + (size_t)MCH*BNC;                // 12288 floats

    dim3 gconv(MCH, Nn/NT, Bn);

    k_w2x_from_x   <<<Bn*Nn, 256, 0, stream>>>(x, mask, c1w2, A);
    k_conv         <<<gconv, 256, 0, stream>>>(xyz, c1w1, A, P);
    k_w2x_from_part<<<Bn*Nn, 256, 0, stream>>>(P, c2w2, A);
    k_conv         <<<gconv, 256, 0, stream>>>(xyz, c2w1, A, P);
    k_reduce_mask  <<<BNC/256, 256, 0, stream>>>(P, mask, X2);
    k_finalize     <<<1, 256, 0, stream>>>(X2, fc2, out);
}